// Round 1
// baseline (499.265 us; speedup 1.0000x reference)
//
#include <hip/hip_runtime.h>
#include <math.h>

#define BATCH   65536
#define N_IN    784
#define DD      10
#define NB      10
#define SD      100   // NB*DD
#define N_OUTS  10

#define ROWS    16
#define BLK     256

// ws layout (floats):
//   0      : Wt      [100][784]   transposed W_in
//   78400  : Wd_eff  [10 t][10 e][100 k]   mask-folded W_data
//   88400  : bd_eff  [10 t][10 e]
//   88500  : Wo_eff  [10 o][10 t][10 e]    any_open-folded W_out
//   89500  : blog    [10 o]
//   total 89510 floats = 358,040 bytes

__global__ void prep_kernel(const float* __restrict__ x,
                            const float* __restrict__ W_in,
                            const float* __restrict__ b_in,
                            const float* __restrict__ W_gate,
                            const float* __restrict__ b_gate,
                            const float* __restrict__ W_data,
                            const float* __restrict__ b_data,
                            const float* __restrict__ W_out,
                            const float* __restrict__ b_out,
                            float* __restrict__ out,
                            float* __restrict__ ws) {
    __shared__ float a0r0[SD];
    __shared__ float mask_l[SD];
    __shared__ float ao_l[NB];
    const int tid = threadIdx.x;

    // step 1: acts0 for batch row 0 (the gate only looks at row 0)
    if (tid < SD) {
        int s = tid / DD, d = tid % DD;
        float acc = b_in[tid];
        for (int i = 0; i < N_IN; ++i)
            acc += x[i] * W_in[s * (N_IN * DD) + i * DD + d];
        a0r0[tid] = fmaxf(acc, 0.f);
    }
    __syncthreads();

    // step 2: gate[s][t] (tid = s*10+t; NB==DD==10 so flat indices coincide)
    if (tid < SD) {
        float g = b_gate[tid];
        int s = tid / DD;
        for (int d = 0; d < DD; ++d)
            g += a0r0[s * DD + d] * W_gate[tid * DD + d];
        mask_l[tid] = (g > 0.f) ? 1.f : 0.f;
    }
    __syncthreads();

    if (tid < NB) {
        float any = 0.f;
        for (int s = 0; s < NB; ++s) any = fmaxf(any, mask_l[s * DD + tid]);
        ao_l[tid] = any;
    }
    if (tid == 0) {
        float sum = 0.f;
        for (int i = 0; i < SD; ++i) sum += mask_l[i];
        out[(long)BATCH * N_OUTS] = sum / 20.0f;   // prob_open_gate
    }
    __syncthreads();

    float* Wt = ws;
    float* Wd = ws + 78400;
    float* bd = ws + 88400;
    float* Wo = ws + 88500;
    float* bl = ws + 89500;

    // Wd_eff[t][e][k] = mask[s,t] * W_data[s][t][d][e],  k = s*10+d
    for (int idx = tid; idx < NB * DD * SD; idx += blockDim.x) {
        int t = idx / (DD * SD);
        int rem = idx % (DD * SD);
        int e = rem / SD;
        int k = rem % SD;
        int s = k / DD, d = k % DD;
        Wd[idx] = mask_l[s * DD + t] * W_data[((s * NB + t) * DD + d) * DD + e];
    }
    // bd_eff[t][e] = sum_s mask[s,t] * b_data[s][t][e]
    for (int idx = tid; idx < NB * DD; idx += blockDim.x) {
        int t = idx / DD, e = idx % DD;
        float v = 0.f;
        for (int s = 0; s < NB; ++s)
            v += mask_l[s * DD + t] * b_data[(s * NB + t) * DD + e];
        bd[idx] = v;
    }
    // Wo_eff[o][t][e] = ao[t] * W_out[t][e][o]
    for (int idx = tid; idx < N_OUTS * NB * DD; idx += blockDim.x) {
        int o = idx / SD;
        int rem = idx % SD;
        int t = rem / DD, e = rem % DD;
        Wo[idx] = ao_l[t] * W_out[(t * DD + e) * N_OUTS + o];
    }
    // blog[o] = sum_t ao[t] * b_out[t][o]
    if (tid < N_OUTS) {
        float v = 0.f;
        for (int t = 0; t < NB; ++t) v += ao_l[t] * b_out[t * N_OUTS + tid];
        bl[tid] = v;
    }
    // Wt[c][i] = W_in[s][i][d], c = s*10+d
    for (int idx = tid; idx < SD * N_IN; idx += blockDim.x) {
        int c = idx / N_IN, i = idx % N_IN;
        Wt[idx] = W_in[(c / DD) * (N_IN * DD) + i * DD + (c % DD)];
    }
}

__global__ __launch_bounds__(BLK) void main_kernel(
        const float* __restrict__ x,
        const float* __restrict__ b_in,
        const float* __restrict__ ws,
        float* __restrict__ out) {
    __shared__ float xs[ROWS * N_IN];     // 12544 floats; reused for routing weights
    __shared__ float a0[ROWS * SD];
    __shared__ float a1[ROWS * SD];
    __shared__ float outs[ROWS * N_OUTS];

    const int tid = threadIdx.x;
    const long row0 = (long)blockIdx.x * ROWS;

    // phase 1: x tile -> LDS (tile is one contiguous 12544-float span)
    {
        const float4* xg = (const float4*)(x + row0 * N_IN);
        float4* xsv = (float4*)xs;
        for (int idx = tid; idx < ROWS * N_IN / 4; idx += BLK)
            xsv[idx] = xg[idx];
    }
    __syncthreads();

    // phase 2: a0[r][c] = relu(x_row . Wt[c] + b_in[c]); k-split across halves
    const int c = tid & 127;
    const int h = tid >> 7;
    float acc[ROWS];
    if (c < SD) {
        const float4* wtv = (const float4*)(ws + c * N_IN);
        #pragma unroll
        for (int r = 0; r < ROWS; ++r) acc[r] = 0.f;
        const int i0 = h * 98;              // in float4 units, 196 total
        for (int ii = i0; ii < i0 + 98; ++ii) {
            float4 w = wtv[ii];
            #pragma unroll
            for (int r = 0; r < ROWS; ++r) {
                float4 xv = *(const float4*)(xs + r * N_IN + ii * 4);
                acc[r] += w.x * xv.x + w.y * xv.y + w.z * xv.z + w.w * xv.w;
            }
        }
    }
    if (h == 0 && c < SD) {
        #pragma unroll
        for (int r = 0; r < ROWS; ++r) a0[r * SD + c] = acc[r];
    }
    __syncthreads();
    if (h == 1 && c < SD) {
        float bi = b_in[c];
        #pragma unroll
        for (int r = 0; r < ROWS; ++r)
            a0[r * SD + c] = fmaxf(a0[r * SD + c] + acc[r] + bi, 0.f);
    }
    __syncthreads();

    // phase 2.5: routing weights -> LDS (reuse xs region; 11110 <= 12544)
    {
        const float* w2 = ws + 78400;
        for (int idx = tid; idx < 11110; idx += BLK) xs[idx] = w2[idx];
    }
    __syncthreads();
    const float* wd  = xs;            // [t][e][k=100]
    const float* bdl = xs + 10000;    // [t][e]
    const float* wo  = xs + 10100;    // [o][t][e]
    const float* bll = xs + 11100;    // [o]

    // phase 3a: a1[r][t*10+e] = relu(bd[t][e] + sum_k a0[r][k]*wd[t][e][k])
    if (tid < ROWS * DD) {
        const int r = tid / DD, e = tid % DD;
        float4 p4[NB];
        #pragma unroll
        for (int t = 0; t < NB; ++t) p4[t] = make_float4(0.f, 0.f, 0.f, 0.f);
        const float4* a0v = (const float4*)(a0 + r * SD);
        for (int k4 = 0; k4 < SD / 4; ++k4) {
            float4 xa = a0v[k4];
            #pragma unroll
            for (int t = 0; t < NB; ++t) {
                float4 w = *(const float4*)(wd + (t * DD + e) * SD + k4 * 4);
                p4[t].x += xa.x * w.x; p4[t].y += xa.y * w.y;
                p4[t].z += xa.z * w.z; p4[t].w += xa.w * w.w;
            }
        }
        #pragma unroll
        for (int t = 0; t < NB; ++t) {
            float p = bdl[t * DD + e] + p4[t].x + p4[t].y + p4[t].z + p4[t].w;
            a1[r * SD + t * DD + e] = fmaxf(p, 0.f);
        }
    }
    __syncthreads();

    // phase 3b: outs[r][o] = blog[o] + sum_{t,e} a1[r][te] * wo[o][te]
    if (tid < ROWS * N_OUTS) {
        const int r = tid / N_OUTS, o = tid % N_OUTS;
        const float4* a1v = (const float4*)(a1 + r * SD);
        const float4* wov = (const float4*)(wo + o * SD);
        float4 L4 = make_float4(0.f, 0.f, 0.f, 0.f);
        for (int q = 0; q < SD / 4; ++q) {
            float4 av = a1v[q], wv = wov[q];
            L4.x += av.x * wv.x; L4.y += av.y * wv.y;
            L4.z += av.z * wv.z; L4.w += av.w * wv.w;
        }
        outs[r * N_OUTS + o] = bll[o] + L4.x + L4.y + L4.z + L4.w;
    }
    __syncthreads();

    // phase 3c: log_softmax per row, coalesced store
    if (tid < ROWS * N_OUTS) {
        const int r = tid / N_OUTS, o = tid % N_OUTS;
        float m = -1e30f;
        for (int j = 0; j < N_OUTS; ++j) m = fmaxf(m, outs[r * N_OUTS + j]);
        float s = 0.f;
        for (int j = 0; j < N_OUTS; ++j) s += expf(outs[r * N_OUTS + j] - m);
        out[(row0 + r) * N_OUTS + o] = outs[r * N_OUTS + o] - m - logf(s);
    }
}

extern "C" void kernel_launch(void* const* d_in, const int* in_sizes, int n_in,
                              void* d_out, int out_size, void* d_ws, size_t ws_size,
                              hipStream_t stream) {
    const float* x      = (const float*)d_in[0];
    const float* W_in   = (const float*)d_in[1];
    const float* b_in   = (const float*)d_in[2];
    const float* W_gate = (const float*)d_in[3];
    const float* b_gate = (const float*)d_in[4];
    const float* W_data = (const float*)d_in[5];
    const float* b_data = (const float*)d_in[6];
    const float* W_out  = (const float*)d_in[7];
    const float* b_out  = (const float*)d_in[8];
    float* out = (float*)d_out;
    float* ws  = (float*)d_ws;

    prep_kernel<<<1, 256, 0, stream>>>(x, W_in, b_in, W_gate, b_gate,
                                       W_data, b_data, W_out, b_out, out, ws);
    main_kernel<<<BATCH / ROWS, BLK, 0, stream>>>(x, b_in, ws, out);
}

// Round 2
// 120.742 us; speedup vs baseline: 4.1350x; 4.1350x over previous
//
#include <hip/hip_runtime.h>
#include <math.h>

#define BATCH   65536
#define N_IN    784
#define DD      10
#define NB      10
#define SD      100
#define N_OUTS  10

typedef float  f32x4  __attribute__((ext_vector_type(4)));
typedef short  bf16x8 __attribute__((ext_vector_type(8)));
typedef short  bf16x4 __attribute__((ext_vector_type(4)));

// ws layout (float offsets)
#define WT_F 0        // bf16 [112][800]  transposed, padded W_in        (44800 floats)
#define WD_F 44800    // bf16 [112 te][128 k] mask-folded W_data         (7168 floats)
#define BD_F 51968    // f32  [100]  bd_eff (te order)
#define WO_F 52068    // f32  [10][112] any_open-folded W_out, zero-pad  (1120 floats)
#define BL_F 53188    // f32  [10]   blog
#define MK_F 53198    // f32  [100]  mask (s*10+t)

__device__ __forceinline__ short f2bf(float f) {
    unsigned u = __builtin_bit_cast(unsigned, f);
    unsigned r = u + 0x7fffu + ((u >> 16) & 1u);   // RNE
    return (short)(r >> 16);
}

__device__ __forceinline__ bf16x8 pack8(float4 lo, float4 hi) {
    bf16x8 v;
    v[0] = f2bf(lo.x); v[1] = f2bf(lo.y); v[2] = f2bf(lo.z); v[3] = f2bf(lo.w);
    v[4] = f2bf(hi.x); v[5] = f2bf(hi.y); v[6] = f2bf(hi.z); v[7] = f2bf(hi.w);
    return v;
}

// ---------------- prep1: exact fp32 gating + small folded tables ----------------
__global__ void prep1_kernel(const float* __restrict__ x,
                             const float* __restrict__ W_in,
                             const float* __restrict__ b_in,
                             const float* __restrict__ W_gate,
                             const float* __restrict__ b_gate,
                             const float* __restrict__ b_data,
                             const float* __restrict__ W_out,
                             const float* __restrict__ b_out,
                             float* __restrict__ out,
                             float* __restrict__ ws) {
    __shared__ float a0r0[SD];
    __shared__ float mask_l[SD];
    __shared__ float ao_l[NB];
    const int tid = threadIdx.x;

    if (tid < SD) {                      // acts0 for batch row 0 (exact fp32)
        int s = tid / DD, d = tid % DD;
        float acc = b_in[tid];
        for (int i = 0; i < N_IN; ++i)
            acc += x[i] * W_in[s * (N_IN * DD) + i * DD + d];
        a0r0[tid] = fmaxf(acc, 0.f);
    }
    __syncthreads();

    if (tid < SD) {                      // gate[s][t] -> mask
        float g = b_gate[tid];
        int s = tid / DD;
        for (int d = 0; d < DD; ++d)
            g += a0r0[s * DD + d] * W_gate[tid * DD + d];
        mask_l[tid] = (g > 0.f) ? 1.f : 0.f;
    }
    __syncthreads();

    if (tid < NB) {
        float any = 0.f;
        for (int s = 0; s < NB; ++s) any = fmaxf(any, mask_l[s * DD + tid]);
        ao_l[tid] = any;
    }
    if (tid == 0) {
        float sum = 0.f;
        for (int i = 0; i < SD; ++i) sum += mask_l[i];
        out[(long)BATCH * N_OUTS] = sum / 20.0f;          // prob_open_gate
    }
    __syncthreads();

    if (tid < SD) ws[MK_F + tid] = mask_l[tid];

    // bd_eff[te] = sum_s mask[s,t] * b_data[s][t][e]
    if (tid < SD) {
        int t = tid / DD, e = tid % DD;
        float v = 0.f;
        for (int s = 0; s < NB; ++s)
            v += mask_l[s * DD + t] * b_data[(s * NB + t) * DD + e];
        ws[BD_F + tid] = v;
    }
    // Wo_eff[o][te] padded to [10][112]
    for (int idx = tid; idx < 10 * 112; idx += blockDim.x) {
        int o = idx / 112, te = idx % 112;
        float v = 0.f;
        if (te < SD) {
            int t = te / DD, e = te % DD;
            v = ao_l[t] * W_out[(t * DD + e) * N_OUTS + o];
        }
        ws[WO_F + idx] = v;
    }
    if (tid < N_OUTS) {
        float v = 0.f;
        for (int t = 0; t < NB; ++t) v += ao_l[t] * b_out[t * N_OUTS + tid];
        ws[BL_F + tid] = v;
    }
}

// ---------------- prep2: bf16 weight tables ----------------
__global__ void prep2_kernel(const float* __restrict__ W_in,
                             const float* __restrict__ W_data,
                             float* __restrict__ ws) {
    short* wt = (short*)(ws + WT_F);
    short* wd = (short*)(ws + WD_F);
    const float* mask = ws + MK_F;
    const int total = 112 * 800 + 112 * 128;
    for (int idx = blockIdx.x * blockDim.x + threadIdx.x; idx < total;
         idx += gridDim.x * blockDim.x) {
        if (idx < 112 * 800) {
            int c = idx / 800, k = idx % 800;
            float v = (c < SD && k < N_IN)
                          ? W_in[(c / DD) * (N_IN * DD) + k * DD + (c % DD)] : 0.f;
            wt[idx] = f2bf(v);
        } else {
            int i2 = idx - 112 * 800;
            int te = i2 / 128, k = i2 % 128;
            float v = 0.f;
            if (te < SD && k < SD) {
                int t = te / DD, e = te % DD, s = k / DD, d = k % DD;
                v = mask[s * DD + t] * W_data[((s * NB + t) * DD + d) * DD + e];
            }
            wd[i2] = f2bf(v);
        }
    }
}

// ---------------- main: MFMA phase2 + MFMA phase3a + VALU phase3b ----------------
__global__ __launch_bounds__(256, 4) void main_kernel(
        const float* __restrict__ x,
        const float* __restrict__ b_in,
        const float* __restrict__ ws,
        float* __restrict__ out) {
    __shared__ __align__(16) short a0b[64 * 136];   // [64 rows][136 bf16] stride 272B

    const int tid  = threadIdx.x;
    const int w    = tid >> 6;
    const int lane = tid & 63;
    const int g    = lane >> 4;
    const int r    = lane & 15;
    const int lrow = w * 16 + r;
    const long grow = (long)blockIdx.x * 64 + lrow;

    const short* wt = (const short*)(ws + WT_F);
    const short* wd = (const short*)(ws + WD_F);

    // ---- phase 2: acts0 = relu(x @ Wt + b_in), MFMA 16x16x32 ----
    f32x4 acc[7];
    #pragma unroll
    for (int ct = 0; ct < 7; ++ct) acc[ct] = (f32x4){0.f, 0.f, 0.f, 0.f};

    const float* xrow = x + grow * N_IN;
    #pragma unroll 2
    for (int k0 = 0; k0 < 768; k0 += 32) {
        float4 lo = *(const float4*)(xrow + k0 + g * 8);
        float4 hi = *(const float4*)(xrow + k0 + g * 8 + 4);
        bf16x8 bfrag = pack8(lo, hi);
        #pragma unroll
        for (int ct = 0; ct < 7; ++ct) {
            bf16x8 afrag = *(const bf16x8*)(wt + (16 * ct + r) * 800 + k0 + g * 8);
            acc[ct] = __builtin_amdgcn_mfma_f32_16x16x32_bf16(afrag, bfrag, acc[ct], 0, 0, 0);
        }
    }
    {   // tail k0 = 768: only k 768..783 valid in x (g<2); Wt is zero-padded
        bf16x8 bfrag = (bf16x8){0, 0, 0, 0, 0, 0, 0, 0};
        if (g < 2) {
            float4 lo = *(const float4*)(xrow + 768 + g * 8);
            float4 hi = *(const float4*)(xrow + 768 + g * 8 + 4);
            bfrag = pack8(lo, hi);
        }
        #pragma unroll
        for (int ct = 0; ct < 7; ++ct) {
            bf16x8 afrag = *(const bf16x8*)(wt + (16 * ct + r) * 800 + 768 + g * 8);
            acc[ct] = __builtin_amdgcn_mfma_f32_16x16x32_bf16(afrag, bfrag, acc[ct], 0, 0, 0);
        }
    }

    // bias + relu, write bf16 acts0 row to LDS (D layout: row=r, c=16ct+4g+j)
    short* myrow = a0b + lrow * 136;
    #pragma unroll
    for (int ct = 0; ct < 7; ++ct) {
        int c0 = 16 * ct + 4 * g;
        bf16x4 pk;
        #pragma unroll
        for (int j = 0; j < 4; ++j) {
            int c = c0 + j;
            float bias = (c < SD) ? b_in[c] : 0.f;
            pk[j] = f2bf(fmaxf(acc[ct][j] + bias, 0.f));
        }
        *(bf16x4*)(myrow + c0) = pk;
    }
    *(bf16x4*)(myrow + 112 + 4 * g) = (bf16x4){0, 0, 0, 0};   // zero cols 112..127

    // ---- phase 3a: acts1 = relu(acts0 @ Wd^T + bd), MFMA, K=128 ----
    f32x4 acc2[7];
    #pragma unroll
    for (int ct = 0; ct < 7; ++ct) acc2[ct] = (f32x4){0.f, 0.f, 0.f, 0.f};
    #pragma unroll
    for (int kk = 0; kk < 4; ++kk) {
        int k0 = kk * 32;
        bf16x8 bfrag = *(const bf16x8*)(myrow + k0 + g * 8);
        #pragma unroll
        for (int ct = 0; ct < 7; ++ct) {
            bf16x8 afrag = *(const bf16x8*)(wd + (16 * ct + r) * 128 + k0 + g * 8);
            acc2[ct] = __builtin_amdgcn_mfma_f32_16x16x32_bf16(afrag, bfrag, acc2[ct], 0, 0, 0);
        }
    }

    float a1r[28];
    #pragma unroll
    for (int ct = 0; ct < 7; ++ct) {
        #pragma unroll
        for (int j = 0; j < 4; ++j) {
            int te = 16 * ct + 4 * g + j;
            float bias = (te < SD) ? ws[BD_F + te] : 0.f;
            a1r[ct * 4 + j] = fmaxf(acc2[ct][j] + bias, 0.f);
        }
    }

    // ---- phase 3b: logits = acts1 @ Wo_eff^T + blog; log_softmax ----
    float part[10];
    #pragma unroll
    for (int o = 0; o < 10; ++o) part[o] = 0.f;
    #pragma unroll
    for (int ct = 0; ct < 7; ++ct) {
        int te0 = 16 * ct + 4 * g;
        #pragma unroll
        for (int o = 0; o < 10; ++o) {
            float4 wv = *(const float4*)(ws + WO_F + o * 112 + te0);
            part[o] += a1r[ct * 4 + 0] * wv.x + a1r[ct * 4 + 1] * wv.y
                     + a1r[ct * 4 + 2] * wv.z + a1r[ct * 4 + 3] * wv.w;
        }
    }
    #pragma unroll
    for (int o = 0; o < 10; ++o) {
        part[o] += __shfl_xor(part[o], 16, 64);
        part[o] += __shfl_xor(part[o], 32, 64);
    }
    if (g == 0) {
        float lg[10];
        float m = -1e30f;
        #pragma unroll
        for (int o = 0; o < 10; ++o) {
            lg[o] = part[o] + ws[BL_F + o];
            m = fmaxf(m, lg[o]);
        }
        float s = 0.f;
        #pragma unroll
        for (int o = 0; o < 10; ++o) s += expf(lg[o] - m);
        float z = m + logf(s);
        float* ob = out + grow * N_OUTS;
        #pragma unroll
        for (int q = 0; q < 5; ++q)
            *(float2*)(ob + 2 * q) = make_float2(lg[2 * q] - z, lg[2 * q + 1] - z);
    }
}

extern "C" void kernel_launch(void* const* d_in, const int* in_sizes, int n_in,
                              void* d_out, int out_size, void* d_ws, size_t ws_size,
                              hipStream_t stream) {
    const float* x      = (const float*)d_in[0];
    const float* W_in   = (const float*)d_in[1];
    const float* b_in   = (const float*)d_in[2];
    const float* W_gate = (const float*)d_in[3];
    const float* b_gate = (const float*)d_in[4];
    const float* W_data = (const float*)d_in[5];
    const float* b_data = (const float*)d_in[6];
    const float* W_out  = (const float*)d_in[7];
    const float* b_out  = (const float*)d_in[8];
    float* out = (float*)d_out;
    float* ws  = (float*)d_ws;

    prep1_kernel<<<1, 256, 0, stream>>>(x, W_in, b_in, W_gate, b_gate,
                                        b_data, W_out, b_out, out, ws);
    prep2_kernel<<<256, 256, 0, stream>>>(W_in, W_data, ws);
    main_kernel<<<BATCH / 64, 256, 0, stream>>>(x, b_in, ws, out);
}